// Round 1
// baseline (425.170 us; speedup 1.0000x reference)
//
#include <hip/hip_runtime.h>
#include <hip/hip_bf16.h>

// Problem constants
#define NT 64      // T trees
#define NF 1024    // F features per tree
#define NB 1024    // B batch
#define ND 2048    // width of d
#define NC 3       // C
#define NK 21      // folded output columns: 2 (clc) + 3 (w1) + 16 (w2 head)
#define NP 27      // partials per (b,t): 5 out5 + 5 cnt5 + 16 o16 + 1 gate
#define NW2ROW 1027

// ws layout (floats):
//   Wp : [NT][NK][ND]  folded weights        = 2,752,512 floats
//   dT : [ND][NB]      transposed d          = 2,097,152 floats
//   ptl: [NT][NP][NB]  per-(t,b) partials    = 1,769,472 floats
#define WP_FLOATS (NT * NK * ND)
#define DT_FLOATS (ND * NB)
#define PTL_FLOATS (NT * NP * NB)

// ---------------------------------------------------------------------------
// Build folded weights: W'[t][k][j] += w*[t][f][k] where j = idx[t][f].
// Collisions are rare (1024 f over 2048 j); fp32 global atomics.
// ---------------------------------------------------------------------------
__global__ __launch_bounds__(256) void scatter_kernel(
    const int* __restrict__ idx, const float* __restrict__ w_clc,
    const float* __restrict__ w1, const float* __restrict__ w2,
    float* __restrict__ Wp)
{
    int tid = blockIdx.x * 256 + threadIdx.x;   // tid = t*NF + f
    if (tid >= NT * NF) return;
    int t = tid >> 10;
    int f = tid & 1023;
    int j = idx[tid];
    float* wpt = Wp + (size_t)t * NK * ND + j;
    atomicAdd(wpt + 0 * ND, w_clc[tid * 2 + 0]);
    atomicAdd(wpt + 1 * ND, w_clc[tid * 2 + 1]);
#pragma unroll
    for (int c = 0; c < 3; ++c) atomicAdd(wpt + (2 + c) * ND, w1[tid * 3 + c]);
    const float* w2row = w2 + (size_t)(t * NW2ROW + f) * 16;
#pragma unroll
    for (int n = 0; n < 16; ++n) atomicAdd(wpt + (5 + n) * ND, w2row[n]);
}

// ---------------------------------------------------------------------------
// Transpose d (NB x ND) -> dT (ND x NB) so the main kernel's lane-along-b
// loads are coalesced.
// ---------------------------------------------------------------------------
__global__ __launch_bounds__(256) void transpose_kernel(
    const float* __restrict__ d, float* __restrict__ dT)
{
    __shared__ float tile[32][33];
    int tx = threadIdx.x & 31;
    int ty = threadIdx.x >> 5;          // 0..7
    int jb = blockIdx.x * 32;
    int bb = blockIdx.y * 32;
#pragma unroll
    for (int r = ty; r < 32; r += 8)
        tile[r][tx] = d[(size_t)(bb + r) * ND + jb + tx];
    __syncthreads();
#pragma unroll
    for (int jr = ty; jr < 32; jr += 8)
        dT[(size_t)(jb + jr) * NB + bb + tx] = tile[tx][jr];
}

// ---------------------------------------------------------------------------
// Main: block = 512 threads = 8 waves. Wave w: t_local = w&3, j_half = w>>2.
// Lane = one b. Each wave accumulates acc[21] over its 1024 j's; j-halves
// reduce through LDS; j_half==0 waves run the (fully lane-local) epilogue
// and emit 27 partials per (t, b).
// ---------------------------------------------------------------------------
__global__ __launch_bounds__(512) void main_kernel(
    const float* __restrict__ dT, const float* __restrict__ Wp,
    const float* __restrict__ b_clc, const float* __restrict__ b1,
    const float* __restrict__ b2, const float* __restrict__ w2,
    const int* __restrict__ cc, float* __restrict__ ptl)
{
    int lane = threadIdx.x & 63;
    int wave = threadIdx.x >> 6;
    int tl = wave & 3;
    int jh = wave >> 2;
    int t = blockIdx.y * 4 + tl;
    int b = blockIdx.x * 64 + lane;

    const float* wp   = Wp + (size_t)t * NK * ND + jh * 1024; // row stride ND
    const float* dcol = dT + (size_t)(jh * 1024) * NB + b;

    float acc[NK];
#pragma unroll
    for (int k = 0; k < NK; ++k) acc[k] = 0.f;

    for (int j = 0; j < 1024; j += 4) {
        float v0 = dcol[(j + 0) * NB];
        float v1 = dcol[(j + 1) * NB];
        float v2 = dcol[(j + 2) * NB];
        float v3 = dcol[(j + 3) * NB];
#pragma unroll
        for (int k = 0; k < NK; ++k) {
            const float* w = wp + k * ND + j;  // wave-uniform address
            float a = acc[k];
            a = fmaf(v0, w[0], a);
            a = fmaf(v1, w[1], a);
            a = fmaf(v2, w[2], a);
            a = fmaf(v3, w[3], a);
            acc[k] = a;
        }
    }

    __shared__ float red[4][NK][64];
    if (jh == 1) {
#pragma unroll
        for (int k = 0; k < NK; ++k) red[tl][k][lane] = acc[k];
    }
    __syncthreads();
    if (jh != 0) return;
#pragma unroll
    for (int k = 0; k < NK; ++k) acc[k] += red[tl][k][lane];

    // ---- epilogue (all lane-local; t-dependent scalars are wave-uniform) ----
    // gate = softmax(clc)[1]
    float L0 = acc[0] + b_clc[t * 2 + 0];
    float L1 = acc[1] + b_clc[t * 2 + 1];
    float mm = fmaxf(L0, L1);
    float e0 = __expf(L0 - mm), e1 = __expf(L1 - mm);
    float gate = e1 / (e0 + e1);

    // p1 = softmax(logits1); relu1
    float l1v[3];
    float m1 = -3.0e38f;
#pragma unroll
    for (int c = 0; c < 3; ++c) {
        l1v[c] = acc[2 + c] + b1[t * 3 + c];
        m1 = fmaxf(m1, l1v[c]);
    }
    float p1[3]; float S1 = 0.f;
#pragma unroll
    for (int c = 0; c < 3; ++c) { p1[c] = __expf(l1v[c] - m1); S1 += p1[c]; }
    float invS1g = gate / S1;

    float r0 = fmaxf(l1v[0], 0.f);
    float r1 = fmaxf(l1v[1], 0.f);
    float r2 = fmaxf(l1v[2], 0.f);

    // l2 = folded head + relu-tail + bias; p2 = softmax(l2)
    const float* w2t = w2 + (size_t)(t * NW2ROW + NF) * 16;
    float l2[16]; float m2 = -3.0e38f;
#pragma unroll
    for (int n = 0; n < 16; ++n) {
        float v = acc[5 + n] + b2[t * 16 + n];
        v = fmaf(r0, w2t[n], v);
        v = fmaf(r1, w2t[16 + n], v);
        v = fmaf(r2, w2t[32 + n], v);
        l2[n] = v;
        m2 = fmaxf(m2, v);
    }
    float S2 = 0.f; float p2[16];
#pragma unroll
    for (int n = 0; n < 16; ++n) { p2[n] = __expf(l2[n] - m2); S2 += p2[n]; }
    float invS2g = gate / S2;

    // out5/count5 contributions (cc entries are wave-uniform)
    float o5[5] = {0, 0, 0, 0, 0};
    float c5[5] = {0, 0, 0, 0, 0};
#pragma unroll
    for (int c = 0; c < 3; ++c) {
        int s = cc[t * 3 + c];
        float pc = p1[c] * invS1g;
#pragma unroll
        for (int x = 0; x < 5; ++x) {
            if (s == x) { o5[x] += pc; c5[x] += gate; }
        }
    }

    float* pt = ptl + (size_t)t * NP * NB + b;
#pragma unroll
    for (int x = 0; x < 5; ++x) pt[x * NB] = o5[x];
#pragma unroll
    for (int x = 0; x < 5; ++x) pt[(5 + x) * NB] = c5[x];
#pragma unroll
    for (int n = 0; n < 16; ++n) pt[(10 + n) * NB] = p2[n] * invS2g;
    pt[26 * NB] = gate;
}

// ---------------------------------------------------------------------------
// Reduce partials over t and finalize output [b][21].
// ---------------------------------------------------------------------------
__global__ __launch_bounds__(256) void finalize_kernel(
    const float* __restrict__ ptl, float* __restrict__ out)
{
    int lane = threadIdx.x & 63;
    int ty = threadIdx.x >> 6;          // 0..3
    int b = blockIdx.x * 64 + lane;

    float s[NP];
#pragma unroll
    for (int k = 0; k < NP; ++k) s[k] = 0.f;
    for (int t = ty; t < NT; t += 4) {
        const float* pt = ptl + (size_t)t * NP * NB + b;
#pragma unroll
        for (int k = 0; k < NP; ++k) s[k] += pt[k * NB];
    }

    __shared__ float red[3][NP][64];
    if (ty > 0) {
#pragma unroll
        for (int k = 0; k < NP; ++k) red[ty - 1][k][lane] = s[k];
    }
    __syncthreads();
    if (ty != 0) return;
#pragma unroll
    for (int r = 0; r < 3; ++r)
#pragma unroll
        for (int k = 0; k < NP; ++k) s[k] += red[r][k][lane];

    float* ob = out + (size_t)b * NK;
#pragma unroll
    for (int x = 0; x < 5; ++x) {
        float c = s[5 + x];
        ob[x] = (c > 0.f) ? (s[x] / c) : 0.f;
    }
    float invg = 1.f / s[26];
#pragma unroll
    for (int n = 0; n < 16; ++n) ob[5 + n] = s[10 + n] * invg;
}

// ---------------------------------------------------------------------------
extern "C" void kernel_launch(void* const* d_in, const int* in_sizes, int n_in,
                              void* d_out, int out_size, void* d_ws, size_t ws_size,
                              hipStream_t stream)
{
    const float* d     = (const float*)d_in[0];
    const int*   idx   = (const int*)  d_in[1];
    const int*   cc    = (const int*)  d_in[2];
    const float* w_clc = (const float*)d_in[3];
    const float* b_clc = (const float*)d_in[4];
    const float* w1    = (const float*)d_in[5];
    const float* b1    = (const float*)d_in[6];
    const float* w2    = (const float*)d_in[7];
    const float* b2    = (const float*)d_in[8];
    float* out = (float*)d_out;

    float* Wp  = (float*)d_ws;
    float* dT  = Wp + WP_FLOATS;
    float* ptl = dT + DT_FLOATS;

    hipMemsetAsync(Wp, 0, (size_t)WP_FLOATS * sizeof(float), stream);
    scatter_kernel<<<(NT * NF) / 256, 256, 0, stream>>>(idx, w_clc, w1, w2, Wp);
    transpose_kernel<<<dim3(ND / 32, NB / 32), 256, 0, stream>>>(d, dT);
    main_kernel<<<dim3(NB / 64, NT / 4), 512, 0, stream>>>(dT, Wp, b_clc, b1, b2, w2, cc, ptl);
    finalize_kernel<<<NB / 64, 256, 0, stream>>>(ptl, out);
}

// Round 2
// 145.560 us; speedup vs baseline: 2.9209x; 2.9209x over previous
//
#include <hip/hip_runtime.h>
#include <hip/hip_bf16.h>

// Problem constants
#define NT 64      // T trees
#define NF 1024    // F features per tree
#define NB 1024    // B batch
#define ND 2048    // width of d
#define NK 21      // folded output columns: 2 (clc) + 3 (w1) + 16 (w2 head)
#define NKP 24     // padded row (6 x float4)
#define NP 27      // partials per (b,t): 5 out5 + 5 cnt5 + 16 o16 + 1 gate
#define NW2ROW 1027
#define JO 4       // j-split factor for main kernel
#define JPB (ND / JO)   // 512 j's per block

// ws layout (floats):
//   Wp  : [NT][ND][NKP] folded weights (k-contiguous) = 3,145,728 floats
//   dT  : [ND][NB]      transposed d                  = 2,097,152 floats
//         (aliased after main_kernel as ptl2 [NT][NP][NB] = 1,769,472 floats)
//   ptl : [NT][JO][NK][NB] j-split partials           = 5,505,024 floats
#define WP_FLOATS ((size_t)NT * ND * NKP)
#define DT_FLOATS ((size_t)ND * NB)
#define PTL_FLOATS ((size_t)NT * JO * NK * NB)

// ---------------------------------------------------------------------------
// Fold weights into Wp[t][j][k] via LDS accumulation (no global atomics, no
// memset needed: every output element is written).
// Grid (2 k-halves, 64 t), block 256.
//   kh=0 -> k 0..11, kh=1 -> k 12..23 (k>=21 stays zero)
// ---------------------------------------------------------------------------
__global__ __launch_bounds__(256) void scatter_kernel(
    const int* __restrict__ idx, const float* __restrict__ w_clc,
    const float* __restrict__ w1, const float* __restrict__ w2,
    float* __restrict__ Wp)
{
    __shared__ float tile[ND][12];   // 98,304 B
    int t = blockIdx.y;
    int kh = blockIdx.x;
    int tid = threadIdx.x;
    int kbase = kh * 12;

    float* tf = &tile[0][0];
    for (int i = tid; i < ND * 12; i += 256) tf[i] = 0.f;
    __syncthreads();

    for (int f = tid; f < NF; f += 256) {
        int j = idx[t * NF + f];
#pragma unroll
        for (int kk = 0; kk < 12; ++kk) {
            int k = kbase + kk;
            float val;
            if (k < 2)       val = w_clc[(t * NF + f) * 2 + k];
            else if (k < 5)  val = w1[(t * NF + f) * 3 + (k - 2)];
            else if (k < 21) val = w2[((size_t)t * NW2ROW + f) * 16 + (k - 5)];
            else             continue;
            atomicAdd(&tile[j][kk], val);
        }
    }
    __syncthreads();

    // write out: 3 float4 per j-row (rows are 48B, 16B-aligned)
    const float4* tf4 = (const float4*)tf;
    for (int i = tid; i < ND * 3; i += 256) {
        int j = i / 3, q = i % 3;
        *(float4*)(Wp + ((size_t)t * ND + j) * NKP + kbase + q * 4) = tf4[i];
    }
}

// ---------------------------------------------------------------------------
// Transpose d (NB x ND) -> dT (ND x NB).
// ---------------------------------------------------------------------------
__global__ __launch_bounds__(256) void transpose_kernel(
    const float* __restrict__ d, float* __restrict__ dT)
{
    __shared__ float tile[32][33];
    int tx = threadIdx.x & 31;
    int ty = threadIdx.x >> 5;          // 0..7
    int jb = blockIdx.x * 32;
    int bb = blockIdx.y * 32;
#pragma unroll
    for (int r = ty; r < 32; r += 8)
        tile[r][tx] = d[(size_t)(bb + r) * ND + jb + tx];
    __syncthreads();
#pragma unroll
    for (int jr = ty; jr < 32; jr += 8)
        dT[(size_t)(jb + jr) * NB + bb + tx] = tile[tx][jr];
}

// ---------------------------------------------------------------------------
// Main contraction. Grid (JO j-quarters, 64 t), block 512 (8 waves).
// Thread handles 2 consecutive b's over the block's 512 j's.
// W'-slice staged in LDS; reads are wave-uniform broadcasts.
// ---------------------------------------------------------------------------
__global__ __launch_bounds__(512) void main_kernel(
    const float* __restrict__ dT, const float* __restrict__ Wp,
    float* __restrict__ ptl)
{
    __shared__ __align__(16) float wl[JPB][NKP];   // 49,152 B
    int tid = threadIdx.x;
    int jo = blockIdx.x;
    int t  = blockIdx.y;
    int jbase = jo * JPB;

    // stage W' slice (coalesced float4 copy: 512*6 float4s)
    {
        const float4* src = (const float4*)(Wp + ((size_t)t * ND + jbase) * NKP);
        float4* dst = (float4*)&wl[0][0];
        for (int i = tid; i < JPB * (NKP / 4); i += 512) dst[i] = src[i];
    }
    __syncthreads();

    int b = tid * 2;
    float acc[NK][2];
#pragma unroll
    for (int k = 0; k < NK; ++k) { acc[k][0] = 0.f; acc[k][1] = 0.f; }

    const float* dcol = dT + (size_t)jbase * NB + b;
#pragma unroll 4
    for (int j = 0; j < JPB; ++j) {
        float2 v = *(const float2*)dcol;
        dcol += NB;
        float wv[NKP];
#pragma unroll
        for (int q = 0; q < NKP / 4; ++q)
            *(float4*)&wv[q * 4] = *(const float4*)&wl[j][q * 4];
#pragma unroll
        for (int k = 0; k < NK; ++k) {
            acc[k][0] = fmaf(v.x, wv[k], acc[k][0]);
            acc[k][1] = fmaf(v.y, wv[k], acc[k][1]);
        }
    }

    float* p = ptl + ((size_t)t * JO + jo) * NK * NB + b;
#pragma unroll
    for (int k = 0; k < NK; ++k)
        *(float2*)(p + (size_t)k * NB) = make_float2(acc[k][0], acc[k][1]);
}

// ---------------------------------------------------------------------------
// Reduce j-split partials + per-(t,b) epilogue -> ptl2[t][27][b].
// Grid (4 b-quarters, 64 t), block 256. All math lane-local; t-scalars uniform.
// ---------------------------------------------------------------------------
__global__ __launch_bounds__(256) void epilogue_kernel(
    const float* __restrict__ ptl, const float* __restrict__ b_clc,
    const float* __restrict__ b1, const float* __restrict__ b2,
    const float* __restrict__ w2, const int* __restrict__ cc,
    float* __restrict__ ptl2)
{
    int t = blockIdx.y;
    int b = blockIdx.x * 256 + threadIdx.x;

    float acc[NK];
#pragma unroll
    for (int k = 0; k < NK; ++k) acc[k] = 0.f;
#pragma unroll
    for (int jo = 0; jo < JO; ++jo) {
        const float* p = ptl + ((size_t)t * JO + jo) * NK * NB + b;
#pragma unroll
        for (int k = 0; k < NK; ++k) acc[k] += p[(size_t)k * NB];
    }

    // gate = softmax(clc)[1]
    float L0 = acc[0] + b_clc[t * 2 + 0];
    float L1 = acc[1] + b_clc[t * 2 + 1];
    float mm = fmaxf(L0, L1);
    float e0 = __expf(L0 - mm), e1 = __expf(L1 - mm);
    float gate = e1 / (e0 + e1);

    // p1 = softmax(logits1); relu
    float l1v[3];
    float m1 = -3.0e38f;
#pragma unroll
    for (int c = 0; c < 3; ++c) {
        l1v[c] = acc[2 + c] + b1[t * 3 + c];
        m1 = fmaxf(m1, l1v[c]);
    }
    float p1[3]; float S1 = 0.f;
#pragma unroll
    for (int c = 0; c < 3; ++c) { p1[c] = __expf(l1v[c] - m1); S1 += p1[c]; }
    float invS1g = gate / S1;

    float r0 = fmaxf(l1v[0], 0.f);
    float r1 = fmaxf(l1v[1], 0.f);
    float r2 = fmaxf(l1v[2], 0.f);

    // l2 = folded head + relu-tail + bias; p2 = softmax(l2)
    const float* w2t = w2 + ((size_t)t * NW2ROW + NF) * 16;
    float l2[16]; float m2 = -3.0e38f;
#pragma unroll
    for (int n = 0; n < 16; ++n) {
        float v = acc[5 + n] + b2[t * 16 + n];
        v = fmaf(r0, w2t[n], v);
        v = fmaf(r1, w2t[16 + n], v);
        v = fmaf(r2, w2t[32 + n], v);
        l2[n] = v;
        m2 = fmaxf(m2, v);
    }
    float S2 = 0.f; float p2[16];
#pragma unroll
    for (int n = 0; n < 16; ++n) { p2[n] = __expf(l2[n] - m2); S2 += p2[n]; }
    float invS2g = gate / S2;

    float o5[5] = {0, 0, 0, 0, 0};
    float c5[5] = {0, 0, 0, 0, 0};
#pragma unroll
    for (int c = 0; c < 3; ++c) {
        int s = cc[t * 3 + c];
        float pc = p1[c] * invS1g;
#pragma unroll
        for (int x = 0; x < 5; ++x) {
            if (s == x) { o5[x] += pc; c5[x] += gate; }
        }
    }

    float* pt = ptl2 + (size_t)t * NP * NB + b;
#pragma unroll
    for (int x = 0; x < 5; ++x) pt[(size_t)x * NB] = o5[x];
#pragma unroll
    for (int x = 0; x < 5; ++x) pt[(size_t)(5 + x) * NB] = c5[x];
#pragma unroll
    for (int n = 0; n < 16; ++n) pt[(size_t)(10 + n) * NB] = p2[n] * invS2g;
    pt[(size_t)26 * NB] = gate;
}

// ---------------------------------------------------------------------------
// Reduce partials over t and finalize output [b][21].
// ---------------------------------------------------------------------------
__global__ __launch_bounds__(256) void finalize_kernel(
    const float* __restrict__ ptl2, float* __restrict__ out)
{
    int lane = threadIdx.x & 63;
    int ty = threadIdx.x >> 6;          // 0..3
    int b = blockIdx.x * 64 + lane;

    float s[NP];
#pragma unroll
    for (int k = 0; k < NP; ++k) s[k] = 0.f;
    for (int t = ty; t < NT; t += 4) {
        const float* pt = ptl2 + (size_t)t * NP * NB + b;
#pragma unroll
        for (int k = 0; k < NP; ++k) s[k] += pt[(size_t)k * NB];
    }

    __shared__ float red[3][NP][64];
    if (ty > 0) {
#pragma unroll
        for (int k = 0; k < NP; ++k) red[ty - 1][k][lane] = s[k];
    }
    __syncthreads();
    if (ty != 0) return;
#pragma unroll
    for (int r = 0; r < 3; ++r)
#pragma unroll
        for (int k = 0; k < NP; ++k) s[k] += red[r][k][lane];

    float* ob = out + (size_t)b * NK;
#pragma unroll
    for (int x = 0; x < 5; ++x) {
        float c = s[5 + x];
        ob[x] = (c > 0.f) ? (s[x] / c) : 0.f;
    }
    float invg = 1.f / s[26];
#pragma unroll
    for (int n = 0; n < 16; ++n) ob[5 + n] = s[10 + n] * invg;
}

// ---------------------------------------------------------------------------
extern "C" void kernel_launch(void* const* d_in, const int* in_sizes, int n_in,
                              void* d_out, int out_size, void* d_ws, size_t ws_size,
                              hipStream_t stream)
{
    const float* d     = (const float*)d_in[0];
    const int*   idx   = (const int*)  d_in[1];
    const int*   cc    = (const int*)  d_in[2];
    const float* w_clc = (const float*)d_in[3];
    const float* b_clc = (const float*)d_in[4];
    const float* w1    = (const float*)d_in[5];
    const float* b1    = (const float*)d_in[6];
    const float* w2    = (const float*)d_in[7];
    const float* b2    = (const float*)d_in[8];
    float* out = (float*)d_out;

    float* Wp   = (float*)d_ws;
    float* dT   = Wp + WP_FLOATS;
    float* ptl  = dT + DT_FLOATS;
    float* ptl2 = dT;   // alias: dT is dead after main_kernel

    scatter_kernel<<<dim3(2, NT), 256, 0, stream>>>(idx, w_clc, w1, w2, Wp);
    transpose_kernel<<<dim3(ND / 32, NB / 32), 256, 0, stream>>>(d, dT);
    main_kernel<<<dim3(JO, NT), 512, 0, stream>>>(dT, Wp, ptl);
    epilogue_kernel<<<dim3(4, NT), 256, 0, stream>>>(ptl, b_clc, b1, b2, w2, cc, ptl2);
    finalize_kernel<<<NB / 64, 256, 0, stream>>>(ptl2, out);
}